// Round 4
// baseline (420.407 us; speedup 1.0000x reference)
//
#include <hip/hip_runtime.h>
#include <stdint.h>

typedef __attribute__((ext_vector_type(4))) float floatx4;
typedef __attribute__((ext_vector_type(8))) short shortx8;

#define LN_EPS 1e-5f

__device__ __forceinline__ unsigned short f2b(float f) {
  unsigned u = __builtin_bit_cast(unsigned, f);
  u = (u + 0x7FFFu + ((u >> 16) & 1u)) >> 16;
  return (unsigned short)u;
}
__device__ __forceinline__ float b2f(unsigned short h) {
  return __builtin_bit_cast(float, (unsigned)h << 16);
}

// async global->LDS 16B: lds dest is wave-uniform base; lane i lands at base + i*16
__device__ __forceinline__ void g2l16(const unsigned short* g, unsigned short* l) {
  __builtin_amdgcn_global_load_lds(
      (const __attribute__((address_space(1))) unsigned int*)g,
      (__attribute__((address_space(3))) unsigned int*)l, 16, 0, 0);
}

// ---------------- block reduction helpers (256 threads = 4 waves) -----------
__device__ __forceinline__ float wave_sum(float v) {
#pragma unroll
  for (int o = 32; o; o >>= 1) v += __shfl_down(v, o, 64);
  return v;
}
__device__ __forceinline__ float wave_max(float v) {
#pragma unroll
  for (int o = 32; o; o >>= 1) v = fmaxf(v, __shfl_down(v, o, 64));
  return v;
}
__device__ __forceinline__ float block_sum(float v, float* s) {
  v = wave_sum(v);
  __syncthreads();
  if ((threadIdx.x & 63) == 0) s[threadIdx.x >> 6] = v;
  __syncthreads();
  return s[0] + s[1] + s[2] + s[3];
}
__device__ __forceinline__ float block_max(float v, float* s) {
  v = wave_max(v);
  __syncthreads();
  if ((threadIdx.x & 63) == 0) s[threadIdx.x >> 6] = v;
  __syncthreads();
  return fmaxf(fmaxf(s[0], s[1]), fmaxf(s[2], s[3]));
}

// ---------------- transpose W (K,N) f32 -> Wt (N,K) bf16 --------------------
__global__ __launch_bounds__(256) void k_transpose_to_bf16(
    const float* __restrict__ in, unsigned short* __restrict__ out, int K, int N) {
  __shared__ float tile[32][33];
  const int k0 = blockIdx.x * 32, n0 = blockIdx.y * 32;
  const int tx = threadIdx.x & 31, ty = threadIdx.x >> 5;  // 32x8
#pragma unroll
  for (int i = 0; i < 32; i += 8)
    tile[ty + i][tx] = in[(long)(k0 + ty + i) * N + n0 + tx];
  __syncthreads();
#pragma unroll
  for (int i = 0; i < 32; i += 8)
    out[(long)(n0 + ty + i) * K + k0 + tx] = f2b(tile[tx][ty + i]);
}

// ---------------- merged transpose of the 3 gate weights (2048x1024) --------
__global__ __launch_bounds__(256) void k_transpose3(
    const float* __restrict__ Wu, const float* __restrict__ Wr,
    const float* __restrict__ Wn, unsigned short* __restrict__ Wtur,
    unsigned short* __restrict__ Wtn) {
  __shared__ float tile[32][33];
  const int which = blockIdx.z;
  const float* in = which == 0 ? Wu : (which == 1 ? Wr : Wn);
  unsigned short* out = which == 0 ? Wtur : (which == 1 ? Wtur + 1024 * 2048 : Wtn);
  const int K = 2048, N = 1024;
  const int k0 = blockIdx.x * 32, n0 = blockIdx.y * 32;
  const int tx = threadIdx.x & 31, ty = threadIdx.x >> 5;
#pragma unroll
  for (int i = 0; i < 32; i += 8)
    tile[ty + i][tx] = in[(long)(k0 + ty + i) * N + n0 + tx];
  __syncthreads();
#pragma unroll
  for (int i = 0; i < 32; i += 8)
    out[(long)(n0 + ty + i) * K + k0 + tx] = f2b(tile[tx][ty + i]);
}

// ---------------- f32 -> bf16 convert ---------------------------------------
__global__ __launch_bounds__(256) void k_cvt_bf16(
    const float* __restrict__ in, unsigned short* __restrict__ out) {
  long i = ((long)blockIdx.x * 256 + threadIdx.x) * 4;
  floatx4 v = *(const floatx4*)(in + i);
  unsigned short t4[4];
#pragma unroll
  for (int j = 0; j < 4; j++) t4[j] = f2b(v[j]);
  *(uint2*)(out + i) = *(uint2*)t4;
}

// ---------------- proj: fused f32-A 128x128 MFMA GEMM, BK=64, XOR swizzle ---
// C[m][n] = toks[m][k](f32) * Wtp[n][k](bf16) + bias[n] -> bf16.
// LDS rows are 128 B; chunk c (16 B) of row r stored at phys chunk c^(r&7):
// conflict-free b128 reads AND g2l16 staging (swizzle applied to the per-lane
// GLOBAL address; lds dest stays lane-contiguous).
__global__ __launch_bounds__(256) void k_proj_f32(
    const float* __restrict__ A, const unsigned short* __restrict__ Bt,
    const float* __restrict__ bias, unsigned short* __restrict__ C) {
  constexpr int K = 768;
  constexpr int N = 1024;
  __shared__ unsigned short As[128 * 64];
  __shared__ unsigned short Bs[128 * 64];
  const int tid = threadIdx.x;
  const int wave = tid >> 6, lane = tid & 63;
  const int id = blockIdx.x;
  const int m0 = (((id >> 6) << 3) + (id & 7)) * 128;  // XCD-aware swizzle
  const int n0 = ((id >> 3) & 7) * 128;
  const int wm = wave & 1, wn = wave >> 1;
  const int l16 = lane & 15, quad = lane >> 4;
  const int brow = lane >> 3;                    // 0..7 in an 8-row group
  const int bchunk = (lane & 7) ^ brow;          // xor-swizzled data chunk

  floatx4 acc[4][4] = {};

  for (int k0 = 0; k0 < K; k0 += 64) {
    // B: async staging, 4 calls/wave, 8 rows (=1024B) each
#pragma unroll
    for (int j = 0; j < 4; j++) {
      const int rb = wave * 32 + j * 8;
      g2l16(Bt + (long)(n0 + rb + brow) * K + k0 + bchunk * 8, &Bs[rb * 64]);
    }
    // A: f32 load + convert + swizzled ds_write_b128 (4 chunks/thread)
#pragma unroll
    for (int i = 0; i < 4; i++) {
      const int cid = i * 256 + tid;
      const int r = cid >> 3, p = cid & 7;
      const int c = p ^ (r & 7);
      const float* src = A + (long)(m0 + r) * K + k0 + c * 8;
      floatx4 v0 = *(const floatx4*)src;
      floatx4 v1 = *(const floatx4*)(src + 4);
      unsigned short t8[8];
#pragma unroll
      for (int q = 0; q < 4; q++) { t8[q] = f2b(v0[q]); t8[4 + q] = f2b(v1[q]); }
      *(uint4*)&As[r * 64 + p * 8] = *(uint4*)t8;
    }
    __syncthreads();

#pragma unroll
    for (int ks = 0; ks < 2; ks++) {
      shortx8 af[4], bf[4];
#pragma unroll
      for (int i = 0; i < 4; i++) {
        const int r = wm * 64 + i * 16 + l16;
        const int c = ks * 4 + quad;
        af[i] = *(const shortx8*)&As[r * 64 + (c ^ (r & 7)) * 8];
      }
#pragma unroll
      for (int j = 0; j < 4; j++) {
        const int r = wn * 64 + j * 16 + l16;
        const int c = ks * 4 + quad;
        bf[j] = *(const shortx8*)&Bs[r * 64 + (c ^ (r & 7)) * 8];
      }
#pragma unroll
      for (int i = 0; i < 4; i++)
#pragma unroll
        for (int j = 0; j < 4; j++)
          acc[i][j] = __builtin_amdgcn_mfma_f32_16x16x32_bf16(af[i], bf[j], acc[i][j], 0, 0, 0);
    }
    __syncthreads();
  }

#pragma unroll
  for (int i = 0; i < 4; i++)
#pragma unroll
    for (int j = 0; j < 4; j++) {
      const int rbase = m0 + wm * 64 + i * 16 + quad * 4;
      const int col = n0 + wn * 64 + j * 16 + l16;
      const float bval = bias[col];
#pragma unroll
      for (int r = 0; r < 4; r++)
        C[(long)(rbase + r) * N + col] = f2b(acc[i][j][r] + bval);
    }
}

// ---------------- generic bf16 MFMA GEMM, 64x64 tile, fused epilogues -------
// modes: 3: out f32  = (1-u)*prev + u*tanh(v+bias)      (cand -> new_state)
//        4: out f32  = v*scale         (scores)
//        5: c<1024: out f32 = sigmoid(v+bias) (u); c>=1024: out2 bf16 = sigmoid(v+bias2)*psn (r)
__global__ __launch_bounds__(256) void k_gemm_bf16(
    const unsigned short* __restrict__ Aptr, int lda, long sA,
    const unsigned short* __restrict__ Bt, int ldb, long sB, int K,
    const float* __restrict__ bias, const float* __restrict__ bias2,
    float scale, int mode,
    void* __restrict__ out, int ldc, long sC, unsigned short* __restrict__ out2,
    const unsigned short* __restrict__ aux_psn,
    const float* __restrict__ aux_u, const float* __restrict__ aux_prev) {
  __shared__ unsigned short As[64 * 40];
  __shared__ unsigned short Bs[64 * 40];
  const int tid = threadIdx.x;
  const int b = blockIdx.z;
  const int m0 = blockIdx.x * 64, n0 = blockIdx.y * 64;
  const int w = tid >> 6, lane = tid & 63;
  const int wm = w & 1, wn = w >> 1;
  const int l16 = lane & 15, quad = lane >> 4;
  const int srow = tid >> 2, skc = (tid & 3) * 8;

  floatx4 acc[2][2] = {};

  for (int k0 = 0; k0 < K; k0 += 32) {
    {
      const unsigned short* src = Aptr + (long)b * sA + (long)(m0 + srow) * lda + k0 + skc;
      *(uint4*)&As[srow * 40 + skc] = *(const uint4*)src;
    }
    {
      const unsigned short* src = Bt + (long)b * sB + (long)(n0 + srow) * ldb + k0 + skc;
      *(uint4*)&Bs[srow * 40 + skc] = *(const uint4*)src;
    }
    __syncthreads();

    shortx8 a0 = *(const shortx8*)&As[(wm * 32 + 0  + l16) * 40 + quad * 8];
    shortx8 a1 = *(const shortx8*)&As[(wm * 32 + 16 + l16) * 40 + quad * 8];
    shortx8 b0 = *(const shortx8*)&Bs[(wn * 32 + 0  + l16) * 40 + quad * 8];
    shortx8 b1 = *(const shortx8*)&Bs[(wn * 32 + 16 + l16) * 40 + quad * 8];
    acc[0][0] = __builtin_amdgcn_mfma_f32_16x16x32_bf16(a0, b0, acc[0][0], 0, 0, 0);
    acc[0][1] = __builtin_amdgcn_mfma_f32_16x16x32_bf16(a0, b1, acc[0][1], 0, 0, 0);
    acc[1][0] = __builtin_amdgcn_mfma_f32_16x16x32_bf16(a1, b0, acc[1][0], 0, 0, 0);
    acc[1][1] = __builtin_amdgcn_mfma_f32_16x16x32_bf16(a1, b1, acc[1][1], 0, 0, 0);
    __syncthreads();
  }

#pragma unroll
  for (int im = 0; im < 2; im++)
#pragma unroll
    for (int in_ = 0; in_ < 2; in_++) {
      const int rbase = m0 + wm * 32 + im * 16 + quad * 4;
      const int c = n0 + wn * 32 + in_ * 16 + l16;
      float bval = 0.0f;
      if (bias) bval = (mode == 5 && c >= 1024) ? bias2[c - 1024] : bias[c];
#pragma unroll
      for (int r = 0; r < 4; r++) {
        const int row = rbase + r;
        float v = acc[im][in_][r] * scale + bval;
        const long cidx = (long)b * sC + (long)row * ldc + c;
        if (mode == 3) {
          float cand = tanhf(v);
          float u = aux_u[(long)row * 1024 + c];
          float p = aux_prev[(long)row * 1024 + c];
          ((float*)out)[cidx] = (1.0f - u) * p + u * cand;
        } else if (mode == 4) {
          ((float*)out)[cidx] = v;
        } else {  // mode 5: merged u|r
          if (c < 1024) {
            ((float*)out)[(long)row * 1024 + c] = 1.0f / (1.0f + expf(-v));
          } else {
            const int cc = c - 1024;
            float rr = 1.0f / (1.0f + expf(-v));
            out2[(long)row * 2048 + cc] = f2b(rr * b2f(aux_psn[(long)row * 2048 + cc]));
          }
        }
      }
    }
}

// ---------------- routed = attn_bf16 @ tok via MFMA, K-split x2 -------------
__global__ __launch_bounds__(256) void k_routed_mfma(
    const unsigned short* __restrict__ attnb,  // [16][64][2048] bf16
    const unsigned short* __restrict__ tok,    // [16][2048][1024] bf16
    float* __restrict__ parts) {
  __shared__ unsigned short As[64 * 40];
  __shared__ unsigned short Bs[32 * 66];
  const int kc = blockIdx.x, nt = blockIdx.y, b = blockIdx.z;
  const int tid = threadIdx.x;
  const int wave = tid >> 6, lane = tid & 63;
  const int wm = wave & 1, wn = wave >> 1;
  const int l16 = lane & 15, quad = lane >> 4;
  const int n0 = nt * 64;
  const long abase = (long)b * 131072 + (long)kc * 1024;
  const long tbase = ((long)b * 2048 + (long)kc * 1024) * 1024;
  const int srow = tid >> 2, skc = (tid & 3) * 8;  // A staging: 64 rows x 32 k
  const int bk = tid >> 3, bd = (tid & 7) * 8;     // B staging: 32 k x 64 d

  floatx4 acc[2][2] = {};

  for (int k0 = 0; k0 < 1024; k0 += 32) {
    *(uint4*)&As[srow * 40 + skc] =
        *(const uint4*)(attnb + abase + (long)srow * 2048 + k0 + skc);
    {
      uint4 v = *(const uint4*)(tok + tbase + (long)(k0 + bk) * 1024 + n0 + bd);
      const unsigned* pv = (const unsigned*)&v;
      unsigned short* dst = &Bs[bk * 66 + bd];
#pragma unroll
      for (int w2 = 0; w2 < 4; w2++) *(unsigned*)(dst + w2 * 2) = pv[w2];
    }
    __syncthreads();

    shortx8 a0 = *(const shortx8*)&As[(wm * 32 + 0  + l16) * 40 + quad * 8];
    shortx8 a1 = *(const shortx8*)&As[(wm * 32 + 16 + l16) * 40 + quad * 8];
    shortx8 b0, b1;
#pragma unroll
    for (int j = 0; j < 8; j++) {
      b0[j] = *(const short*)&Bs[(quad * 8 + j) * 66 + wn * 32 + l16];
      b1[j] = *(const short*)&Bs[(quad * 8 + j) * 66 + wn * 32 + 16 + l16];
    }
    acc[0][0] = __builtin_amdgcn_mfma_f32_16x16x32_bf16(a0, b0, acc[0][0], 0, 0, 0);
    acc[0][1] = __builtin_amdgcn_mfma_f32_16x16x32_bf16(a0, b1, acc[0][1], 0, 0, 0);
    acc[1][0] = __builtin_amdgcn_mfma_f32_16x16x32_bf16(a1, b0, acc[1][0], 0, 0, 0);
    acc[1][1] = __builtin_amdgcn_mfma_f32_16x16x32_bf16(a1, b1, acc[1][1], 0, 0, 0);
    __syncthreads();
  }

#pragma unroll
  for (int im = 0; im < 2; im++)
#pragma unroll
    for (int in_ = 0; in_ < 2; in_++) {
      const int rbase = wm * 32 + im * 16 + quad * 4;
      const int c = n0 + wn * 32 + in_ * 16 + l16;
#pragma unroll
      for (int r = 0; r < 4; r++)
        parts[(long)kc * 1048576 + ((long)b * 64 + rbase + r) * 1024 + c] =
            acc[im][in_][r];
    }
}

// ---------------- softmax over S=2048; writes bf16 --------------------------
__global__ __launch_bounds__(256) void k_softmax(
    const float* __restrict__ scores, unsigned short* __restrict__ attnb) {
  __shared__ float scr[4];
  const float* row = scores + (long)blockIdx.x * 2048;
  const int t = threadIdx.x;
  floatx4 a = *(const floatx4*)(row + t * 8);
  floatx4 b = *(const floatx4*)(row + t * 8 + 4);
  float m = -1e30f;
#pragma unroll
  for (int i = 0; i < 4; i++) m = fmaxf(m, fmaxf(a[i], b[i]));
  m = block_max(m, scr);
  float s = 0.f;
#pragma unroll
  for (int i = 0; i < 4; i++) { a[i] = expf(a[i] - m); s += a[i]; b[i] = expf(b[i] - m); s += b[i]; }
  s = block_sum(s, scr);
  const float inv = 1.0f / s;
  unsigned short t8[8];
#pragma unroll
  for (int i = 0; i < 4; i++) { t8[i] = f2b(a[i] * inv); t8[4 + i] = f2b(b[i] * inv); }
  *(uint4*)(attnb + (long)blockIdx.x * 2048 + t * 8) = *(uint4*)t8;
}

// ---------------- merged LayerNorms: prev->conc[:, :D], parts->conc/candA ---
__global__ __launch_bounds__(256) void k_ln2(
    const float* __restrict__ prev, const float* __restrict__ parts,
    const float* __restrict__ g_st, const float* __restrict__ be_st,
    const float* __restrict__ g_in, const float* __restrict__ be_in,
    unsigned short* __restrict__ conc, unsigned short* __restrict__ candA) {
  __shared__ float scr[4];
  const long r = blockIdx.x & 1023;
  const bool second = blockIdx.x >= 1024;
  const int t = threadIdx.x;
  floatx4 v;
  const float *g, *be;
  if (!second) {
    v = *(const floatx4*)(prev + r * 1024 + t * 4);
    g = g_st; be = be_st;
  } else {
    v = *(const floatx4*)(parts + r * 1024 + t * 4);
    v += *(const floatx4*)(parts + 1048576 + r * 1024 + t * 4);
    g = g_in; be = be_in;
  }
  float s1 = v[0] + v[1] + v[2] + v[3];
  float s2 = v[0] * v[0] + v[1] * v[1] + v[2] * v[2] + v[3] * v[3];
  s1 = block_sum(s1, scr);
  s2 = block_sum(s2, scr);
  const float mean = s1 * (1.0f / 1024.0f);
  const float var = s2 * (1.0f / 1024.0f) - mean * mean;
  const float rstd = rsqrtf(var + LN_EPS);
#pragma unroll
  for (int i = 0; i < 4; i++) {
    const int d = t * 4 + i;
    const float y = (v[i] - mean) * rstd * g[d] + be[d];
    const unsigned short h = f2b(y);
    if (!second) {
      conc[r * 2048 + d] = h;
    } else {
      conc[r * 2048 + 1024 + d] = h;
      candA[r * 2048 + 1024 + d] = h;
    }
  }
}

// ---------------- final LayerNorm -> f32 output ------------------------------
__global__ __launch_bounds__(256) void k_ln_out(
    const float* __restrict__ in, const float* __restrict__ g,
    const float* __restrict__ be, float* __restrict__ out) {
  __shared__ float scr[4];
  const long r = blockIdx.x;
  const int t = threadIdx.x;
  floatx4 v = *(const floatx4*)(in + r * 1024 + t * 4);
  float s1 = v[0] + v[1] + v[2] + v[3];
  float s2 = v[0] * v[0] + v[1] * v[1] + v[2] * v[2] + v[3] * v[3];
  s1 = block_sum(s1, scr);
  s2 = block_sum(s2, scr);
  const float mean = s1 * (1.0f / 1024.0f);
  const float var = s2 * (1.0f / 1024.0f) - mean * mean;
  const float rstd = rsqrtf(var + LN_EPS);
  floatx4 o;
#pragma unroll
  for (int i = 0; i < 4; i++) {
    const int d = t * 4 + i;
    o[i] = (v[i] - mean) * rstd * g[d] + be[d];
  }
  *(floatx4*)(out + r * 1024 + t * 4) = o;
}

// ---------------------------------------------------------------------------
extern "C" void kernel_launch(void* const* d_in, const int* in_sizes, int n_in,
                              void* d_out, int out_size, void* d_ws, size_t ws_size,
                              hipStream_t stream) {
  (void)in_sizes; (void)n_in; (void)out_size; (void)ws_size;
  const float* prev  = (const float*)d_in[0];
  const float* toks  = (const float*)d_in[1];
  const float* Wp    = (const float*)d_in[2];
  const float* bp    = (const float*)d_in[3];
  const float* g_st  = (const float*)d_in[4];
  const float* be_st = (const float*)d_in[5];
  const float* g_in  = (const float*)d_in[6];
  const float* be_in = (const float*)d_in[7];
  const float* g_o   = (const float*)d_in[8];
  const float* be_o  = (const float*)d_in[9];
  const float* Wu    = (const float*)d_in[10];
  const float* bu    = (const float*)d_in[11];
  const float* Wr    = (const float*)d_in[12];
  const float* br    = (const float*)d_in[13];
  const float* Wn    = (const float*)d_in[14];
  const float* bn    = (const float*)d_in[15];
  float* out = (float*)d_out;

  // ---- workspace (~116 MB, no aliasing)
  char* ws = (char*)d_ws;
  unsigned short* tok   = (unsigned short*)ws; ws += 67108864;   // 32768x1024 bf16
  unsigned short* Wtp   = (unsigned short*)ws; ws += 1572864;    // 1024x768 bf16
  unsigned short* psb   = (unsigned short*)ws; ws += 2097152;    // 1024x1024 bf16
  float*          attn  = (float*)ws;          ws += 8388608;    // 16x64x2048 f32
  unsigned short* attnb = (unsigned short*)ws; ws += 4194304;    // 16x64x2048 bf16
  float*          parts = (float*)ws;          ws += 8388608;    // 2x 1024x1024 f32
  unsigned short* conc  = (unsigned short*)ws; ws += 4194304;    // 1024x2048 bf16
  unsigned short* candA = (unsigned short*)ws; ws += 4194304;    // 1024x2048 bf16
  float*          ubuf  = (float*)ws;          ws += 4194304;    // 1024x1024 f32
  float*          ns    = (float*)ws;          ws += 4194304;    // 1024x1024 f32
  unsigned short* Wtur  = (unsigned short*)ws; ws += 8388608;    // 2048x2048 bf16
  unsigned short* Wtn   = (unsigned short*)ws; ws += 4194304;    // 1024x2048 bf16

  const dim3 blk(256);

  // 1. W_proj transpose (B operand of proj)
  k_transpose_to_bf16<<<dim3(24, 32), blk, 0, stream>>>(Wp, Wtp, 768, 1024);
  // 2. prev -> bf16 (A of scores)
  k_cvt_bf16<<<dim3(1024), blk, 0, stream>>>(prev, psb);
  // 3. proj: tok = toks(f32) @ W_proj + b_proj, fused cvt, XCD-swizzled
  k_proj_f32<<<dim3(2048), blk, 0, stream>>>(toks, Wtp, bp, tok);
  // 4. gate weights, one kernel
  k_transpose3<<<dim3(64, 32, 3), blk, 0, stream>>>(Wu, Wr, Wn, Wtur, Wtn);
  // 5. scores = prev @ tok^T / 32  (mode 4)
  k_gemm_bf16<<<dim3(1, 32, 16), blk, 0, stream>>>(
      psb, 1024, 65536L, tok, 1024, 2097152L, 1024,
      nullptr, nullptr, 0.03125f, 4, (void*)attn, 2048, 131072L,
      nullptr, nullptr, nullptr, nullptr);
  // 6. softmax (f32 in, bf16 out)
  k_softmax<<<dim3(1024), blk, 0, stream>>>(attn, attnb);
  // 7. routed partials via MFMA (K-split x2)
  k_routed_mfma<<<dim3(2, 16, 16), blk, 0, stream>>>(attnb, tok, parts);
  // 8. both LayerNorms
  k_ln2<<<dim3(2048), blk, 0, stream>>>(prev, parts, g_st, be_st, g_in, be_in,
                                        conc, candA);
  // 9. merged u|r gates (mode 5)
  k_gemm_bf16<<<dim3(16, 32, 1), blk, 0, stream>>>(
      conc, 2048, 0L, Wtur, 2048, 0L, 2048,
      bu, br, 1.0f, 5, (void*)ubuf, 1024, 0L, candA, conc, nullptr, nullptr);
  // 10. new_state via mode 3
  k_gemm_bf16<<<dim3(16, 16, 1), blk, 0, stream>>>(
      candA, 2048, 0L, Wtn, 2048, 0L, 2048,
      bn, nullptr, 1.0f, 3, (void*)ns, 1024, 0L, nullptr, nullptr, ubuf, prev);
  // 11. final LN -> output
  k_ln_out<<<dim3(1024), blk, 0, stream>>>(ns, g_o, be_o, out);
}

// Round 5
// 406.064 us; speedup vs baseline: 1.0353x; 1.0353x over previous
//
#include <hip/hip_runtime.h>
#include <stdint.h>

typedef __attribute__((ext_vector_type(4))) float floatx4;
typedef __attribute__((ext_vector_type(8))) short shortx8;

#define LN_EPS 1e-5f

__device__ __forceinline__ unsigned short f2b(float f) {
  unsigned u = __builtin_bit_cast(unsigned, f);
  u = (u + 0x7FFFu + ((u >> 16) & 1u)) >> 16;
  return (unsigned short)u;
}
__device__ __forceinline__ float b2f(unsigned short h) {
  return __builtin_bit_cast(float, (unsigned)h << 16);
}

// async global->LDS 16B: lds dest is wave-uniform base; lane i lands at base + i*16
__device__ __forceinline__ void g2l16(const unsigned short* g, unsigned short* l) {
  __builtin_amdgcn_global_load_lds(
      (const __attribute__((address_space(1))) unsigned int*)g,
      (__attribute__((address_space(3))) unsigned int*)l, 16, 0, 0);
}

// ---------------- block reduction helpers (256 threads = 4 waves) -----------
__device__ __forceinline__ float wave_sum(float v) {
#pragma unroll
  for (int o = 32; o; o >>= 1) v += __shfl_down(v, o, 64);
  return v;
}
__device__ __forceinline__ float wave_max(float v) {
#pragma unroll
  for (int o = 32; o; o >>= 1) v = fmaxf(v, __shfl_down(v, o, 64));
  return v;
}
__device__ __forceinline__ float block_sum(float v, float* s) {
  v = wave_sum(v);
  __syncthreads();
  if ((threadIdx.x & 63) == 0) s[threadIdx.x >> 6] = v;
  __syncthreads();
  return s[0] + s[1] + s[2] + s[3];
}
__device__ __forceinline__ float block_max(float v, float* s) {
  v = wave_max(v);
  __syncthreads();
  if ((threadIdx.x & 63) == 0) s[threadIdx.x >> 6] = v;
  __syncthreads();
  return fmaxf(fmaxf(s[0], s[1]), fmaxf(s[2], s[3]));
}

// ---------------- transpose W (K,N) f32 -> Wt (N,K) bf16 --------------------
__global__ __launch_bounds__(256) void k_transpose_to_bf16(
    const float* __restrict__ in, unsigned short* __restrict__ out, int K, int N) {
  __shared__ float tile[32][33];
  const int k0 = blockIdx.x * 32, n0 = blockIdx.y * 32;
  const int tx = threadIdx.x & 31, ty = threadIdx.x >> 5;  // 32x8
#pragma unroll
  for (int i = 0; i < 32; i += 8)
    tile[ty + i][tx] = in[(long)(k0 + ty + i) * N + n0 + tx];
  __syncthreads();
#pragma unroll
  for (int i = 0; i < 32; i += 8)
    out[(long)(n0 + ty + i) * K + k0 + tx] = f2b(tile[tx][ty + i]);
}

// ---------------- merged transpose of the 3 gate weights (2048x1024) --------
__global__ __launch_bounds__(256) void k_transpose3(
    const float* __restrict__ Wu, const float* __restrict__ Wr,
    const float* __restrict__ Wn, unsigned short* __restrict__ Wtur,
    unsigned short* __restrict__ Wtn) {
  __shared__ float tile[32][33];
  const int which = blockIdx.z;
  const float* in = which == 0 ? Wu : (which == 1 ? Wr : Wn);
  unsigned short* out = which == 0 ? Wtur : (which == 1 ? Wtur + 1024 * 2048 : Wtn);
  const int K = 2048, N = 1024;
  const int k0 = blockIdx.x * 32, n0 = blockIdx.y * 32;
  const int tx = threadIdx.x & 31, ty = threadIdx.x >> 5;
#pragma unroll
  for (int i = 0; i < 32; i += 8)
    tile[ty + i][tx] = in[(long)(k0 + ty + i) * N + n0 + tx];
  __syncthreads();
#pragma unroll
  for (int i = 0; i < 32; i += 8)
    out[(long)(n0 + ty + i) * K + k0 + tx] = f2b(tile[tx][ty + i]);
}

// ---------------- f32 -> bf16 convert ---------------------------------------
__global__ __launch_bounds__(256) void k_cvt_bf16(
    const float* __restrict__ in, unsigned short* __restrict__ out) {
  long i = ((long)blockIdx.x * 256 + threadIdx.x) * 4;
  floatx4 v = *(const floatx4*)(in + i);
  unsigned short t4[4];
#pragma unroll
  for (int j = 0; j < 4; j++) t4[j] = f2b(v[j]);
  *(uint2*)(out + i) = *(uint2*)t4;
}

// ---------------- proj: bf16 128x128 MFMA GEMM, BK=64, XOR swizzle ----------
// C[m][n] = A[m][k] * Bt[n][k] + bias[n] -> bf16. K=768, N=1024.
// LDS rows 128 B (64 bf16); chunk c of row r at phys c^(r&7): conflict-free
// b128 reads; g2l16 staging carries the swizzle in the per-lane global addr.
__global__ __launch_bounds__(256) void k_proj128(
    const unsigned short* __restrict__ A, const unsigned short* __restrict__ Bt,
    const float* __restrict__ bias, unsigned short* __restrict__ C) {
  constexpr int K = 768;
  constexpr int N = 1024;
  __shared__ unsigned short As[128 * 64];
  __shared__ unsigned short Bs[128 * 64];
  const int tid = threadIdx.x;
  const int wave = tid >> 6, lane = tid & 63;
  const int id = blockIdx.x;
  const int m0 = (((id >> 6) << 3) + (id & 7)) * 128;  // XCD-aware swizzle
  const int n0 = ((id >> 3) & 7) * 128;
  const int wm = wave & 1, wn = wave >> 1;
  const int l16 = lane & 15, quad = lane >> 4;
  const int srow8 = lane >> 3;   // 0..7
  const int schunk = lane & 7;   // phys chunk this lane fills

  floatx4 acc[4][4] = {};

  for (int k0 = 0; k0 < K; k0 += 64) {
#pragma unroll
    for (int j = 0; j < 4; j++) {
      const int rb = wave * 32 + j * 8;
      const int rA = rb + srow8;
      const int c = schunk ^ (rA & 7);
      g2l16(A + (long)(m0 + rA) * K + k0 + c * 8, &As[rb * 64]);
      g2l16(Bt + (long)(n0 + rA) * K + k0 + c * 8, &Bs[rb * 64]);
    }
    __syncthreads();

#pragma unroll
    for (int ks = 0; ks < 2; ks++) {
      shortx8 af[4], bf[4];
#pragma unroll
      for (int i = 0; i < 4; i++) {
        const int r = wm * 64 + i * 16 + l16;
        af[i] = *(const shortx8*)&As[r * 64 + ((ks * 4 + quad) ^ (r & 7)) * 8];
      }
#pragma unroll
      for (int j = 0; j < 4; j++) {
        const int r = wn * 64 + j * 16 + l16;
        bf[j] = *(const shortx8*)&Bs[r * 64 + ((ks * 4 + quad) ^ (r & 7)) * 8];
      }
#pragma unroll
      for (int i = 0; i < 4; i++)
#pragma unroll
        for (int j = 0; j < 4; j++)
          acc[i][j] = __builtin_amdgcn_mfma_f32_16x16x32_bf16(af[i], bf[j], acc[i][j], 0, 0, 0);
    }
    __syncthreads();
  }

#pragma unroll
  for (int i = 0; i < 4; i++)
#pragma unroll
    for (int j = 0; j < 4; j++) {
      const int rbase = m0 + wm * 64 + i * 16 + quad * 4;
      const int col = n0 + wn * 64 + j * 16 + l16;
      const float bval = bias[col];
#pragma unroll
      for (int r = 0; r < 4; r++)
        C[(long)(rbase + r) * N + col] = f2b(acc[i][j][r] + bval);
    }
}

// ---------------- generic 64x128 MFMA GEMM, BK=64, swizzled, g2l16 ----------
// C[m][n] = A[m][k] * Bt[n][k]; modes:
//  3: out f32 = (1-u)*prev + u*tanh(v+bias)                (cand->new_state)
//  4: out f32 = v*scale                                    (scores)
//  5: c<1024: out f32 = sigmoid(v+bias); else out2 bf16 = sigmoid(v+bias2)*psn
__global__ __launch_bounds__(256) void k_gemm64x128(
    const unsigned short* __restrict__ A, long sA, int lda,
    const unsigned short* __restrict__ Bt, long sB, int ldb, int K,
    const float* __restrict__ bias, const float* __restrict__ bias2,
    float scale, int mode,
    void* __restrict__ out, int ldc, long sC, unsigned short* __restrict__ out2,
    const unsigned short* __restrict__ aux_psn,
    const float* __restrict__ aux_u, const float* __restrict__ aux_prev) {
  __shared__ unsigned short As[64 * 64];    // 8 KB
  __shared__ unsigned short Bs[128 * 64];   // 16 KB
  const int tid = threadIdx.x;
  const int wave = tid >> 6, lane = tid & 63;
  const int b = blockIdx.z;
  const int m0 = blockIdx.x * 64, n0 = blockIdx.y * 128;
  const int wm = wave & 1, wn = wave >> 1;
  const int l16 = lane & 15, quad = lane >> 4;
  const int srow8 = lane >> 3;
  const int schunk = lane & 7;
  const unsigned short* Ab = A + (long)b * sA;
  const unsigned short* Bb = Bt + (long)b * sB;

  floatx4 acc[2][4] = {};

  for (int k0 = 0; k0 < K; k0 += 64) {
#pragma unroll
    for (int j = 0; j < 2; j++) {
      const int rb = wave * 16 + j * 8;
      const int r = rb + srow8;
      const int c = schunk ^ (r & 7);
      g2l16(Ab + (long)(m0 + r) * lda + k0 + c * 8, &As[rb * 64]);
    }
#pragma unroll
    for (int j = 0; j < 4; j++) {
      const int rb = wave * 32 + j * 8;
      const int r = rb + srow8;
      const int c = schunk ^ (r & 7);
      g2l16(Bb + (long)(n0 + r) * ldb + k0 + c * 8, &Bs[rb * 64]);
    }
    __syncthreads();

#pragma unroll
    for (int ks = 0; ks < 2; ks++) {
      shortx8 af[2], bf[4];
#pragma unroll
      for (int i = 0; i < 2; i++) {
        const int r = wm * 32 + i * 16 + l16;
        af[i] = *(const shortx8*)&As[r * 64 + ((ks * 4 + quad) ^ (r & 7)) * 8];
      }
#pragma unroll
      for (int j = 0; j < 4; j++) {
        const int r = wn * 64 + j * 16 + l16;
        bf[j] = *(const shortx8*)&Bs[r * 64 + ((ks * 4 + quad) ^ (r & 7)) * 8];
      }
#pragma unroll
      for (int i = 0; i < 2; i++)
#pragma unroll
        for (int j = 0; j < 4; j++)
          acc[i][j] = __builtin_amdgcn_mfma_f32_16x16x32_bf16(af[i], bf[j], acc[i][j], 0, 0, 0);
    }
    __syncthreads();
  }

#pragma unroll
  for (int i = 0; i < 2; i++)
#pragma unroll
    for (int j = 0; j < 4; j++) {
      const int rbase = m0 + wm * 32 + i * 16 + quad * 4;
      const int c = n0 + wn * 64 + j * 16 + l16;
      float bval = 0.0f;
      if (bias) bval = (mode == 5 && c >= 1024) ? bias2[c - 1024] : bias[c];
#pragma unroll
      for (int r = 0; r < 4; r++) {
        const int row = rbase + r;
        float v = acc[i][j][r] * scale + bval;
        const long cidx = (long)b * sC + (long)row * ldc + c;
        if (mode == 3) {
          float cand = tanhf(v);
          float u = aux_u[(long)row * 1024 + c];
          float p = aux_prev[(long)row * 1024 + c];
          ((float*)out)[cidx] = (1.0f - u) * p + u * cand;
        } else if (mode == 4) {
          ((float*)out)[cidx] = v;
        } else {  // mode 5
          if (c < 1024) {
            ((float*)out)[(long)row * 1024 + c] = 1.0f / (1.0f + expf(-v));
          } else {
            const int cc = c - 1024;
            float rr = 1.0f / (1.0f + expf(-v));
            out2[(long)row * 2048 + cc] = f2b(rr * b2f(aux_psn[(long)row * 2048 + cc]));
          }
        }
      }
    }
}

// ---------------- routed = attn_bf16 @ tok via MFMA, K-split x2 -------------
__global__ __launch_bounds__(256) void k_routed_mfma(
    const unsigned short* __restrict__ attnb,  // [16][64][2048] bf16
    const unsigned short* __restrict__ tok,    // [16][2048][1024] bf16
    float* __restrict__ parts) {
  __shared__ unsigned short As[64 * 40];
  __shared__ unsigned short Bs[32 * 66];
  const int kc = blockIdx.x, nt = blockIdx.y, b = blockIdx.z;
  const int tid = threadIdx.x;
  const int wave = tid >> 6, lane = tid & 63;
  const int wm = wave & 1, wn = wave >> 1;
  const int l16 = lane & 15, quad = lane >> 4;
  const int n0 = nt * 64;
  const long abase = (long)b * 131072 + (long)kc * 1024;
  const long tbase = ((long)b * 2048 + (long)kc * 1024) * 1024;
  const int srow = tid >> 2, skc = (tid & 3) * 8;  // A staging: 64 rows x 32 k
  const int bk = tid >> 3, bd = (tid & 7) * 8;     // B staging: 32 k x 64 d

  floatx4 acc[2][2] = {};

  for (int k0 = 0; k0 < 1024; k0 += 32) {
    *(uint4*)&As[srow * 40 + skc] =
        *(const uint4*)(attnb + abase + (long)srow * 2048 + k0 + skc);
    {
      uint4 v = *(const uint4*)(tok + tbase + (long)(k0 + bk) * 1024 + n0 + bd);
      const unsigned* pv = (const unsigned*)&v;
      unsigned short* dst = &Bs[bk * 66 + bd];
#pragma unroll
      for (int w2 = 0; w2 < 4; w2++) *(unsigned*)(dst + w2 * 2) = pv[w2];
    }
    __syncthreads();

    shortx8 a0 = *(const shortx8*)&As[(wm * 32 + 0  + l16) * 40 + quad * 8];
    shortx8 a1 = *(const shortx8*)&As[(wm * 32 + 16 + l16) * 40 + quad * 8];
    shortx8 b0, b1;
#pragma unroll
    for (int j = 0; j < 8; j++) {
      b0[j] = *(const short*)&Bs[(quad * 8 + j) * 66 + wn * 32 + l16];
      b1[j] = *(const short*)&Bs[(quad * 8 + j) * 66 + wn * 32 + 16 + l16];
    }
    acc[0][0] = __builtin_amdgcn_mfma_f32_16x16x32_bf16(a0, b0, acc[0][0], 0, 0, 0);
    acc[0][1] = __builtin_amdgcn_mfma_f32_16x16x32_bf16(a0, b1, acc[0][1], 0, 0, 0);
    acc[1][0] = __builtin_amdgcn_mfma_f32_16x16x32_bf16(a1, b0, acc[1][0], 0, 0, 0);
    acc[1][1] = __builtin_amdgcn_mfma_f32_16x16x32_bf16(a1, b1, acc[1][1], 0, 0, 0);
    __syncthreads();
  }

#pragma unroll
  for (int im = 0; im < 2; im++)
#pragma unroll
    for (int in_ = 0; in_ < 2; in_++) {
      const int rbase = wm * 32 + im * 16 + quad * 4;
      const int c = n0 + wn * 32 + in_ * 16 + l16;
#pragma unroll
      for (int r = 0; r < 4; r++)
        parts[(long)kc * 1048576 + ((long)b * 64 + rbase + r) * 1024 + c] =
            acc[im][in_][r];
    }
}

// ---------------- softmax over S=2048; writes bf16 --------------------------
__global__ __launch_bounds__(256) void k_softmax(
    const float* __restrict__ scores, unsigned short* __restrict__ attnb) {
  __shared__ float scr[4];
  const float* row = scores + (long)blockIdx.x * 2048;
  const int t = threadIdx.x;
  floatx4 a = *(const floatx4*)(row + t * 8);
  floatx4 b = *(const floatx4*)(row + t * 8 + 4);
  float m = -1e30f;
#pragma unroll
  for (int i = 0; i < 4; i++) m = fmaxf(m, fmaxf(a[i], b[i]));
  m = block_max(m, scr);
  float s = 0.f;
#pragma unroll
  for (int i = 0; i < 4; i++) { a[i] = expf(a[i] - m); s += a[i]; b[i] = expf(b[i] - m); s += b[i]; }
  s = block_sum(s, scr);
  const float inv = 1.0f / s;
  unsigned short t8[8];
#pragma unroll
  for (int i = 0; i < 4; i++) { t8[i] = f2b(a[i] * inv); t8[4 + i] = f2b(b[i] * inv); }
  *(uint4*)(attnb + (long)blockIdx.x * 2048 + t * 8) = *(uint4*)t8;
}

// ---------------- merged LayerNorms: prev->conc[:, :D], parts->conc/candA ---
__global__ __launch_bounds__(256) void k_ln2(
    const float* __restrict__ prev, const float* __restrict__ parts,
    const float* __restrict__ g_st, const float* __restrict__ be_st,
    const float* __restrict__ g_in, const float* __restrict__ be_in,
    unsigned short* __restrict__ conc, unsigned short* __restrict__ candA) {
  __shared__ float scr[4];
  const long r = blockIdx.x & 1023;
  const bool second = blockIdx.x >= 1024;
  const int t = threadIdx.x;
  floatx4 v;
  const float *g, *be;
  if (!second) {
    v = *(const floatx4*)(prev + r * 1024 + t * 4);
    g = g_st; be = be_st;
  } else {
    v = *(const floatx4*)(parts + r * 1024 + t * 4);
    v += *(const floatx4*)(parts + 1048576 + r * 1024 + t * 4);
    g = g_in; be = be_in;
  }
  float s1 = v[0] + v[1] + v[2] + v[3];
  float s2 = v[0] * v[0] + v[1] * v[1] + v[2] * v[2] + v[3] * v[3];
  s1 = block_sum(s1, scr);
  s2 = block_sum(s2, scr);
  const float mean = s1 * (1.0f / 1024.0f);
  const float var = s2 * (1.0f / 1024.0f) - mean * mean;
  const float rstd = rsqrtf(var + LN_EPS);
#pragma unroll
  for (int i = 0; i < 4; i++) {
    const int d = t * 4 + i;
    const float y = (v[i] - mean) * rstd * g[d] + be[d];
    const unsigned short h = f2b(y);
    if (!second) {
      conc[r * 2048 + d] = h;
    } else {
      conc[r * 2048 + 1024 + d] = h;
      candA[r * 2048 + 1024 + d] = h;
    }
  }
}

// ---------------- final LayerNorm -> f32 output ------------------------------
__global__ __launch_bounds__(256) void k_ln_out(
    const float* __restrict__ in, const float* __restrict__ g,
    const float* __restrict__ be, float* __restrict__ out) {
  __shared__ float scr[4];
  const long r = blockIdx.x;
  const int t = threadIdx.x;
  floatx4 v = *(const floatx4*)(in + r * 1024 + t * 4);
  float s1 = v[0] + v[1] + v[2] + v[3];
  float s2 = v[0] * v[0] + v[1] * v[1] + v[2] * v[2] + v[3] * v[3];
  s1 = block_sum(s1, scr);
  s2 = block_sum(s2, scr);
  const float mean = s1 * (1.0f / 1024.0f);
  const float var = s2 * (1.0f / 1024.0f) - mean * mean;
  const float rstd = rsqrtf(var + LN_EPS);
  floatx4 o;
#pragma unroll
  for (int i = 0; i < 4; i++) {
    const int d = t * 4 + i;
    o[i] = (v[i] - mean) * rstd * g[d] + be[d];
  }
  *(floatx4*)(out + r * 1024 + t * 4) = o;
}

// ---------------------------------------------------------------------------
extern "C" void kernel_launch(void* const* d_in, const int* in_sizes, int n_in,
                              void* d_out, int out_size, void* d_ws, size_t ws_size,
                              hipStream_t stream) {
  (void)in_sizes; (void)n_in; (void)out_size; (void)ws_size;
  const float* prev  = (const float*)d_in[0];
  const float* toks  = (const float*)d_in[1];
  const float* Wp    = (const float*)d_in[2];
  const float* bp    = (const float*)d_in[3];
  const float* g_st  = (const float*)d_in[4];
  const float* be_st = (const float*)d_in[5];
  const float* g_in  = (const float*)d_in[6];
  const float* be_in = (const float*)d_in[7];
  const float* g_o   = (const float*)d_in[8];
  const float* be_o  = (const float*)d_in[9];
  const float* Wu    = (const float*)d_in[10];
  const float* bu    = (const float*)d_in[11];
  const float* Wr    = (const float*)d_in[12];
  const float* br    = (const float*)d_in[13];
  const float* Wn    = (const float*)d_in[14];
  const float* bn    = (const float*)d_in[15];
  float* out = (float*)d_out;

  // ---- workspace (~118 MB). tokb (dead after proj) aliases region U, which
  // holds everything produced/consumed strictly after proj.
  char* ws = (char*)d_ws;
  unsigned short* tok   = (unsigned short*)ws; ws += 67108864;   // 32768x1024 bf16
  unsigned short* Wtp   = (unsigned short*)ws; ws += 1572864;    // 1024x768 bf16
  unsigned short* psb   = (unsigned short*)ws; ws += 2097152;    // 1024x1024 bf16
  char* U = ws;
  unsigned short* tokb  = (unsigned short*)U;                    // 32768x768 bf16 (50.3MB)
  char* u = U;
  float*          attn  = (float*)u;          u += 8388608;      // 16x64x2048 f32
  unsigned short* attnb = (unsigned short*)u; u += 4194304;      // 16x64x2048 bf16
  float*          parts = (float*)u;          u += 8388608;      // 2x 1024x1024 f32
  unsigned short* conc  = (unsigned short*)u; u += 4194304;      // 1024x2048 bf16
  unsigned short* candA = (unsigned short*)u; u += 4194304;      // 1024x2048 bf16
  float*          ubuf  = (float*)u;          u += 4194304;      // 1024x1024 f32
  float*          ns    = (float*)u;          u += 4194304;      // 1024x1024 f32
  unsigned short* Wtur  = (unsigned short*)u; u += 8388608;      // 2048x2048 bf16
  unsigned short* Wtn   = (unsigned short*)u; u += 4194304;      // 1024x2048 bf16

  const dim3 blk(256);

  // 1. W_proj transpose (B operand of proj)
  k_transpose_to_bf16<<<dim3(24, 32), blk, 0, stream>>>(Wp, Wtp, 768, 1024);
  // 2. prev -> bf16 (A of scores)
  k_cvt_bf16<<<dim3(1024), blk, 0, stream>>>(prev, psb);
  // 3. toks -> bf16 (memory-bound clean pass; keeps proj VALU-light)
  k_cvt_bf16<<<dim3(24576), blk, 0, stream>>>(toks, tokb);
  // 4. proj: tok = tokb @ W_proj + b_proj, XCD-swizzled 128x128, BK=64
  k_proj128<<<dim3(2048), blk, 0, stream>>>(tokb, Wtp, bp, tok);
  // 5. gate weight transposes (writes into U - tokb dead now)
  k_transpose3<<<dim3(64, 32, 3), blk, 0, stream>>>(Wu, Wr, Wn, Wtur, Wtn);
  // 6. scores = prev @ tok^T / 32  (mode 4), 64x128 tiles
  k_gemm64x128<<<dim3(1, 16, 16), blk, 0, stream>>>(
      psb, 65536L, 1024, tok, 2097152L, 1024, 1024,
      nullptr, nullptr, 0.03125f, 4, (void*)attn, 2048, 131072L,
      nullptr, nullptr, nullptr, nullptr);
  // 7. softmax (f32 in, bf16 out)
  k_softmax<<<dim3(1024), blk, 0, stream>>>(attn, attnb);
  // 8. routed partials via MFMA (K-split x2)
  k_routed_mfma<<<dim3(2, 16, 16), blk, 0, stream>>>(attnb, tok, parts);
  // 9. both LayerNorms
  k_ln2<<<dim3(2048), blk, 0, stream>>>(prev, parts, g_st, be_st, g_in, be_in,
                                        conc, candA);
  // 10. merged u|r gates (mode 5)
  k_gemm64x128<<<dim3(16, 16, 1), blk, 0, stream>>>(
      conc, 0L, 2048, Wtur, 0L, 2048, 2048,
      bu, br, 1.0f, 5, (void*)ubuf, 1024, 0L, candA, conc, nullptr, nullptr);
  // 11. new_state via mode 3
  k_gemm64x128<<<dim3(16, 8, 1), blk, 0, stream>>>(
      candA, 0L, 2048, Wtn, 0L, 2048, 2048,
      bn, nullptr, 1.0f, 3, (void*)ns, 1024, 0L, nullptr, nullptr, ubuf, prev);
  // 12. final LN -> output
  k_ln_out<<<dim3(1024), blk, 0, stream>>>(ns, g_o, be_o, out);
}

// Round 6
// 369.263 us; speedup vs baseline: 1.1385x; 1.0997x over previous
//
#include <hip/hip_runtime.h>
#include <stdint.h>

typedef __attribute__((ext_vector_type(4))) float floatx4;
typedef __attribute__((ext_vector_type(8))) short shortx8;

#define LN_EPS 1e-5f

__device__ __forceinline__ unsigned short f2b(float f) {
  unsigned u = __builtin_bit_cast(unsigned, f);
  u = (u + 0x7FFFu + ((u >> 16) & 1u)) >> 16;
  return (unsigned short)u;
}
__device__ __forceinline__ float b2f(unsigned short h) {
  return __builtin_bit_cast(float, (unsigned)h << 16);
}

// async global->LDS 16B: lds dest is wave-uniform base; lane i lands at base + i*16
__device__ __forceinline__ void g2l16(const unsigned short* g, unsigned short* l) {
  __builtin_amdgcn_global_load_lds(
      (const __attribute__((address_space(1))) unsigned int*)g,
      (__attribute__((address_space(3))) unsigned int*)l, 16, 0, 0);
}

// ---------------- block reduction helpers (256 threads = 4 waves) -----------
__device__ __forceinline__ float wave_sum(float v) {
#pragma unroll
  for (int o = 32; o; o >>= 1) v += __shfl_down(v, o, 64);
  return v;
}
__device__ __forceinline__ float block_sum(float v, float* s) {
  v = wave_sum(v);
  __syncthreads();
  if ((threadIdx.x & 63) == 0) s[threadIdx.x >> 6] = v;
  __syncthreads();
  return s[0] + s[1] + s[2] + s[3];
}

// ---------------- transpose W_proj (768,1024) f32 -> (1024,768) bf16 --------
__global__ __launch_bounds__(256) void k_transpose_to_bf16(
    const float* __restrict__ in, unsigned short* __restrict__ out, int K, int N) {
  __shared__ float tile[32][33];
  const int k0 = blockIdx.x * 32, n0 = blockIdx.y * 32;
  const int tx = threadIdx.x & 31, ty = threadIdx.x >> 5;
#pragma unroll
  for (int i = 0; i < 32; i += 8)
    tile[ty + i][tx] = in[(long)(k0 + ty + i) * N + n0 + tx];
  __syncthreads();
#pragma unroll
  for (int i = 0; i < 32; i += 8)
    out[(long)(n0 + ty + i) * K + k0 + tx] = f2b(tile[tx][ty + i]);
}

// ---------------- merged transpose of the 3 gate weights (2048x1024) --------
__global__ __launch_bounds__(256) void k_transpose3(
    const float* __restrict__ Wu, const float* __restrict__ Wr,
    const float* __restrict__ Wn, unsigned short* __restrict__ Wtur,
    unsigned short* __restrict__ Wtn) {
  __shared__ float tile[32][33];
  const int which = blockIdx.z;
  const float* in = which == 0 ? Wu : (which == 1 ? Wr : Wn);
  unsigned short* out = which == 0 ? Wtur : (which == 1 ? Wtur + 1024 * 2048 : Wtn);
  const int K = 2048, N = 1024;
  const int k0 = blockIdx.x * 32, n0 = blockIdx.y * 32;
  const int tx = threadIdx.x & 31, ty = threadIdx.x >> 5;
#pragma unroll
  for (int i = 0; i < 32; i += 8)
    tile[ty + i][tx] = in[(long)(k0 + ty + i) * N + n0 + tx];
  __syncthreads();
#pragma unroll
  for (int i = 0; i < 32; i += 8)
    out[(long)(n0 + ty + i) * K + k0 + tx] = f2b(tile[tx][ty + i]);
}

// ---------------- merged f32 -> bf16 convert: prev then toks ---------------
__global__ __launch_bounds__(256) void k_cvt2(
    const float* __restrict__ prev, unsigned short* __restrict__ psb,
    const float* __restrict__ toks, unsigned short* __restrict__ tokb) {
  const long chunk = (long)blockIdx.x * 256 + threadIdx.x;  // 4 elems per chunk
  const float* src;
  unsigned short* dst;
  long i;
  if (chunk < 262144) { src = prev; dst = psb; i = chunk * 4; }
  else { src = toks; dst = tokb; i = (chunk - 262144) * 4; }
  floatx4 v = *(const floatx4*)(src + i);
  unsigned short t4[4];
#pragma unroll
  for (int j = 0; j < 4; j++) t4[j] = f2b(v[j]);
  *(uint2*)(dst + i) = *(uint2*)t4;
}

// ---------------- proj: bf16 128x128 MFMA, BK=64, swizzle, hoisted addrs ----
__global__ __launch_bounds__(256) void k_proj128(
    const unsigned short* __restrict__ A, const unsigned short* __restrict__ Bt,
    const float* __restrict__ bias, unsigned short* __restrict__ C) {
  constexpr int K = 768;
  constexpr int N = 1024;
  __shared__ unsigned short As[128 * 64];
  __shared__ unsigned short Bs[128 * 64];
  const int tid = threadIdx.x;
  const int wave = tid >> 6, lane = tid & 63;
  const int id = blockIdx.x;
  const int m0 = (((id >> 6) << 3) + (id & 7)) * 128;  // XCD-aware swizzle
  const int n0 = ((id >> 3) & 7) * 128;
  const int wm = wave & 1, wn = wave >> 1;
  const int l16 = lane & 15, quad = lane >> 4;
  const int srow8 = lane >> 3;
  const int c8 = ((lane & 7) ^ srow8) * 8;  // constant swizzled k-chunk

  // hoisted staging pointers
  const unsigned short* gA[4];
  const unsigned short* gB[4];
  unsigned short* lA[4];
  unsigned short* lB[4];
#pragma unroll
  for (int j = 0; j < 4; j++) {
    const int rb = wave * 32 + j * 8;
    gA[j] = A + (long)(m0 + rb + srow8) * K + c8;
    gB[j] = Bt + (long)(n0 + rb + srow8) * K + c8;
    lA[j] = &As[rb * 64];
    lB[j] = &Bs[rb * 64];
  }
  // hoisted fragment LDS offsets
  int offA[2][4], offB[2][4];
#pragma unroll
  for (int ks = 0; ks < 2; ks++)
#pragma unroll
    for (int i = 0; i < 4; i++) {
      int r = wm * 64 + i * 16 + l16;
      offA[ks][i] = r * 64 + (((ks * 4 + quad) ^ (r & 7)) * 8);
      r = wn * 64 + i * 16 + l16;
      offB[ks][i] = r * 64 + (((ks * 4 + quad) ^ (r & 7)) * 8);
    }

  floatx4 acc[4][4] = {};

  for (int k0 = 0; k0 < K; k0 += 64) {
#pragma unroll
    for (int j = 0; j < 4; j++) {
      g2l16(gA[j] + k0, lA[j]);
      g2l16(gB[j] + k0, lB[j]);
    }
    __syncthreads();
#pragma unroll
    for (int ks = 0; ks < 2; ks++) {
      shortx8 af[4], bf[4];
#pragma unroll
      for (int i = 0; i < 4; i++) af[i] = *(const shortx8*)&As[offA[ks][i]];
#pragma unroll
      for (int j = 0; j < 4; j++) bf[j] = *(const shortx8*)&Bs[offB[ks][j]];
#pragma unroll
      for (int i = 0; i < 4; i++)
#pragma unroll
        for (int j = 0; j < 4; j++)
          acc[i][j] = __builtin_amdgcn_mfma_f32_16x16x32_bf16(af[i], bf[j], acc[i][j], 0, 0, 0);
    }
    __syncthreads();
  }

#pragma unroll
  for (int i = 0; i < 4; i++)
#pragma unroll
    for (int j = 0; j < 4; j++) {
      const int rbase = m0 + wm * 64 + i * 16 + quad * 4;
      const int col = n0 + wn * 64 + j * 16 + l16;
      const float bval = bias[col];
#pragma unroll
      for (int r = 0; r < 4; r++)
        C[(long)(rbase + r) * N + col] = f2b(acc[i][j][r] + bval);
    }
}

// ---------------- generic 64x64 MFMA GEMM, BK=64, swizzled, g2l16 -----------
// C[m][n] = A[m][k]*Bt[n][k]; z decomposes to (batch b, k-chunk kc).
// modes: 0: out2 bf16 = exp(v*scale)                     (scores->attnb)
//        3: out f32  = (1-u)*prev + u*tanh(v+bias)       (cand->new_state)
//        5: c<1024: out f32 = sigmoid(v+bias); else out2 bf16 = sigmoid(v+bias2)*psn
__global__ __launch_bounds__(256) void k_gemm64(
    const unsigned short* __restrict__ A, long sAb, long sAk, int lda,
    const unsigned short* __restrict__ Bt, long sBb, long sBk, int ldb,
    int K, int nsplit,
    const float* __restrict__ bias, const float* __restrict__ bias2,
    float scale, int mode,
    void* __restrict__ out, int ldc, long sCb, long sCk,
    unsigned short* __restrict__ out2,
    const unsigned short* __restrict__ aux_psn,
    const float* __restrict__ aux_u, const float* __restrict__ aux_prev) {
  __shared__ unsigned short As[64 * 64];
  __shared__ unsigned short Bs[64 * 64];
  const int tid = threadIdx.x;
  const int wave = tid >> 6, lane = tid & 63;
  const int z = blockIdx.z;
  const int b = (nsplit == 2) ? (z >> 1) : z;
  const int kc = (nsplit == 2) ? (z & 1) : 0;
  const int m0 = blockIdx.x * 64, n0 = blockIdx.y * 64;
  const int wm = wave & 1, wn = wave >> 1;
  const int l16 = lane & 15, quad = lane >> 4;
  const int srow8 = lane >> 3;
  const int c8 = ((lane & 7) ^ srow8) * 8;
  const unsigned short* Ab = A + (long)b * sAb + (long)kc * sAk;
  const unsigned short* Bb = Bt + (long)b * sBb + (long)kc * sBk;

  const unsigned short* gA[2];
  const unsigned short* gB[2];
  unsigned short* lA[2];
  unsigned short* lB[2];
#pragma unroll
  for (int j = 0; j < 2; j++) {
    const int rb = wave * 16 + j * 8;
    gA[j] = Ab + (long)(m0 + rb + srow8) * lda + c8;
    gB[j] = Bb + (long)(n0 + rb + srow8) * ldb + c8;
    lA[j] = &As[rb * 64];
    lB[j] = &Bs[rb * 64];
  }
  int offA[2][2], offB[2][2];
#pragma unroll
  for (int ks = 0; ks < 2; ks++)
#pragma unroll
    for (int i = 0; i < 2; i++) {
      int r = wm * 32 + i * 16 + l16;
      offA[ks][i] = r * 64 + (((ks * 4 + quad) ^ (r & 7)) * 8);
      r = wn * 32 + i * 16 + l16;
      offB[ks][i] = r * 64 + (((ks * 4 + quad) ^ (r & 7)) * 8);
    }

  floatx4 acc[2][2] = {};

  for (int k0 = 0; k0 < K; k0 += 64) {
#pragma unroll
    for (int j = 0; j < 2; j++) {
      g2l16(gA[j] + k0, lA[j]);
      g2l16(gB[j] + k0, lB[j]);
    }
    __syncthreads();
#pragma unroll
    for (int ks = 0; ks < 2; ks++) {
      shortx8 af[2], bf[2];
#pragma unroll
      for (int i = 0; i < 2; i++) af[i] = *(const shortx8*)&As[offA[ks][i]];
#pragma unroll
      for (int j = 0; j < 2; j++) bf[j] = *(const shortx8*)&Bs[offB[ks][j]];
#pragma unroll
      for (int i = 0; i < 2; i++)
#pragma unroll
        for (int j = 0; j < 2; j++)
          acc[i][j] = __builtin_amdgcn_mfma_f32_16x16x32_bf16(af[i], bf[j], acc[i][j], 0, 0, 0);
    }
    __syncthreads();
  }

#pragma unroll
  for (int i = 0; i < 2; i++)
#pragma unroll
    for (int j = 0; j < 2; j++) {
      const int rbase = m0 + wm * 32 + i * 16 + quad * 4;
      const int c = n0 + wn * 32 + j * 16 + l16;
      float bval = 0.0f;
      if (bias) bval = (mode == 5 && c >= 1024) ? bias2[c - 1024] : bias[c];
#pragma unroll
      for (int r = 0; r < 4; r++) {
        const int row = rbase + r;
        float v = acc[i][j][r] * scale + bval;
        const long cidx = (long)b * sCb + (long)kc * sCk + (long)row * ldc + c;
        if (mode == 0) {
          out2[cidx] = f2b(expf(v));
        } else if (mode == 3) {
          float cand = tanhf(v);
          float u = aux_u[(long)row * 1024 + c];
          float p = aux_prev[(long)row * 1024 + c];
          ((float*)out)[cidx] = (1.0f - u) * p + u * cand;
        } else {  // mode 5
          if (c < 1024) {
            ((float*)out)[(long)row * 1024 + c] = 1.0f / (1.0f + expf(-v));
          } else {
            const int cc = c - 1024;
            float rr = 1.0f / (1.0f + expf(-v));
            out2[(long)row * 2048 + cc] = f2b(rr * b2f(aux_psn[(long)row * 2048 + cc]));
          }
        }
      }
    }
}

// ---------------- routed = attnb(exp) @ tok via MFMA, K-split x2 ------------
__global__ __launch_bounds__(256) void k_routed_mfma(
    const unsigned short* __restrict__ attnb,  // [16][64][2048] bf16 (unnormalized exp)
    const unsigned short* __restrict__ tok,    // [16][2048][1024] bf16
    float* __restrict__ parts) {
  __shared__ unsigned short As[64 * 40];
  __shared__ unsigned short Bs[32 * 66];
  const int kc = blockIdx.x, nt = blockIdx.y, b = blockIdx.z;
  const int tid = threadIdx.x;
  const int wave = tid >> 6, lane = tid & 63;
  const int wm = wave & 1, wn = wave >> 1;
  const int l16 = lane & 15, quad = lane >> 4;
  const int n0 = nt * 64;
  const long abase = (long)b * 131072 + (long)kc * 1024;
  const long tbase = ((long)b * 2048 + (long)kc * 1024) * 1024;
  const int srow = tid >> 2, skc = (tid & 3) * 8;
  const int bk = tid >> 3, bd = (tid & 7) * 8;

  floatx4 acc[2][2] = {};

  for (int k0 = 0; k0 < 1024; k0 += 32) {
    *(uint4*)&As[srow * 40 + skc] =
        *(const uint4*)(attnb + abase + (long)srow * 2048 + k0 + skc);
    {
      uint4 v = *(const uint4*)(tok + tbase + (long)(k0 + bk) * 1024 + n0 + bd);
      const unsigned* pv = (const unsigned*)&v;
      unsigned short* dst = &Bs[bk * 66 + bd];
#pragma unroll
      for (int w2 = 0; w2 < 4; w2++) *(unsigned*)(dst + w2 * 2) = pv[w2];
    }
    __syncthreads();

    shortx8 a0 = *(const shortx8*)&As[(wm * 32 + 0  + l16) * 40 + quad * 8];
    shortx8 a1 = *(const shortx8*)&As[(wm * 32 + 16 + l16) * 40 + quad * 8];
    shortx8 b0, b1;
#pragma unroll
    for (int j = 0; j < 8; j++) {
      b0[j] = *(const short*)&Bs[(quad * 8 + j) * 66 + wn * 32 + l16];
      b1[j] = *(const short*)&Bs[(quad * 8 + j) * 66 + wn * 32 + 16 + l16];
    }
    acc[0][0] = __builtin_amdgcn_mfma_f32_16x16x32_bf16(a0, b0, acc[0][0], 0, 0, 0);
    acc[0][1] = __builtin_amdgcn_mfma_f32_16x16x32_bf16(a0, b1, acc[0][1], 0, 0, 0);
    acc[1][0] = __builtin_amdgcn_mfma_f32_16x16x32_bf16(a1, b0, acc[1][0], 0, 0, 0);
    acc[1][1] = __builtin_amdgcn_mfma_f32_16x16x32_bf16(a1, b1, acc[1][1], 0, 0, 0);
    __syncthreads();
  }

#pragma unroll
  for (int im = 0; im < 2; im++)
#pragma unroll
    for (int in_ = 0; in_ < 2; in_++) {
      const int rbase = wm * 32 + im * 16 + quad * 4;
      const int c = n0 + wn * 32 + in_ * 16 + l16;
#pragma unroll
      for (int r = 0; r < 4; r++)
        parts[(long)kc * 1048576 + ((long)b * 64 + rbase + r) * 1024 + c] =
            acc[im][in_][r];
    }
}

// ---------------- merged LayerNorms: prev->conc[:, :D], parts->conc/candA ---
// LN is scale-invariant, so unnormalized exp-weighted parts are fine.
__global__ __launch_bounds__(256) void k_ln2(
    const float* __restrict__ prev, const float* __restrict__ parts,
    const float* __restrict__ g_st, const float* __restrict__ be_st,
    const float* __restrict__ g_in, const float* __restrict__ be_in,
    unsigned short* __restrict__ conc, unsigned short* __restrict__ candA) {
  __shared__ float scr[4];
  const long r = blockIdx.x & 1023;
  const bool second = blockIdx.x >= 1024;
  const int t = threadIdx.x;
  floatx4 v;
  const float *g, *be;
  if (!second) {
    v = *(const floatx4*)(prev + r * 1024 + t * 4);
    g = g_st; be = be_st;
  } else {
    v = *(const floatx4*)(parts + r * 1024 + t * 4);
    v += *(const floatx4*)(parts + 1048576 + r * 1024 + t * 4);
    g = g_in; be = be_in;
  }
  float s1 = v[0] + v[1] + v[2] + v[3];
  float s2 = v[0] * v[0] + v[1] * v[1] + v[2] * v[2] + v[3] * v[3];
  s1 = block_sum(s1, scr);
  s2 = block_sum(s2, scr);
  const float mean = s1 * (1.0f / 1024.0f);
  const float var = s2 * (1.0f / 1024.0f) - mean * mean;
  const float rstd = rsqrtf(var + LN_EPS);
#pragma unroll
  for (int i = 0; i < 4; i++) {
    const int d = t * 4 + i;
    const float y = (v[i] - mean) * rstd * g[d] + be[d];
    const unsigned short h = f2b(y);
    if (!second) {
      conc[r * 2048 + d] = h;
    } else {
      conc[r * 2048 + 1024 + d] = h;
      candA[r * 2048 + 1024 + d] = h;
    }
  }
}

// ---------------- final LayerNorm -> f32 output ------------------------------
__global__ __launch_bounds__(256) void k_ln_out(
    const float* __restrict__ in, const float* __restrict__ g,
    const float* __restrict__ be, float* __restrict__ out) {
  __shared__ float scr[4];
  const long r = blockIdx.x;
  const int t = threadIdx.x;
  floatx4 v = *(const floatx4*)(in + r * 1024 + t * 4);
  float s1 = v[0] + v[1] + v[2] + v[3];
  float s2 = v[0] * v[0] + v[1] * v[1] + v[2] * v[2] + v[3] * v[3];
  s1 = block_sum(s1, scr);
  s2 = block_sum(s2, scr);
  const float mean = s1 * (1.0f / 1024.0f);
  const float var = s2 * (1.0f / 1024.0f) - mean * mean;
  const float rstd = rsqrtf(var + LN_EPS);
  floatx4 o;
#pragma unroll
  for (int i = 0; i < 4; i++) {
    const int d = t * 4 + i;
    o[i] = (v[i] - mean) * rstd * g[d] + be[d];
  }
  *(floatx4*)(out + r * 1024 + t * 4) = o;
}

// ---------------------------------------------------------------------------
extern "C" void kernel_launch(void* const* d_in, const int* in_sizes, int n_in,
                              void* d_out, int out_size, void* d_ws, size_t ws_size,
                              hipStream_t stream) {
  (void)in_sizes; (void)n_in; (void)out_size; (void)ws_size;
  const float* prev  = (const float*)d_in[0];
  const float* toks  = (const float*)d_in[1];
  const float* Wp    = (const float*)d_in[2];
  const float* bp    = (const float*)d_in[3];
  const float* g_st  = (const float*)d_in[4];
  const float* be_st = (const float*)d_in[5];
  const float* g_in  = (const float*)d_in[6];
  const float* be_in = (const float*)d_in[7];
  const float* g_o   = (const float*)d_in[8];
  const float* be_o  = (const float*)d_in[9];
  const float* Wu    = (const float*)d_in[10];
  const float* bu    = (const float*)d_in[11];
  const float* Wr    = (const float*)d_in[12];
  const float* br    = (const float*)d_in[13];
  const float* Wn    = (const float*)d_in[14];
  const float* bn    = (const float*)d_in[15];
  float* out = (float*)d_out;

  // ---- workspace (~118 MB). tokb (dead after proj) aliases region U.
  char* ws = (char*)d_ws;
  unsigned short* tok   = (unsigned short*)ws; ws += 67108864;   // 32768x1024 bf16
  unsigned short* Wtp   = (unsigned short*)ws; ws += 1572864;    // 1024x768 bf16
  unsigned short* psb   = (unsigned short*)ws; ws += 2097152;    // 1024x1024 bf16
  char* U = ws;
  unsigned short* tokb  = (unsigned short*)U;                    // 32768x768 bf16 (50.3MB)
  char* u = U;
  unsigned short* attnb = (unsigned short*)u; u += 4194304;      // 16x64x2048 bf16
  float*          parts = (float*)u;          u += 8388608;      // 2x 1024x1024 f32
  unsigned short* conc  = (unsigned short*)u; u += 4194304;      // 1024x2048 bf16
  unsigned short* candA = (unsigned short*)u; u += 4194304;      // 1024x2048 bf16
  float*          ubuf  = (float*)u;          u += 4194304;      // 1024x1024 f32
  float*          ns    = (float*)u;          u += 4194304;      // 1024x1024 f32
  unsigned short* Wtur  = (unsigned short*)u; u += 8388608;      // 2048x2048 bf16
  unsigned short* Wtn   = (unsigned short*)u; u += 4194304;      // 1024x2048 bf16

  const dim3 blk(256);

  // 1. prev + toks -> bf16 (one launch)
  k_cvt2<<<dim3(25600), blk, 0, stream>>>(prev, psb, toks, tokb);
  // 2. W_proj transpose
  k_transpose_to_bf16<<<dim3(24, 32), blk, 0, stream>>>(Wp, Wtp, 768, 1024);
  // 3. proj: tok = tokb @ W_proj + b_proj, XCD-swizzled 128x128, BK=64
  k_proj128<<<dim3(2048), blk, 0, stream>>>(tokb, Wtp, bp, tok);
  // 4. gate weight transposes (into U - tokb dead now)
  k_transpose3<<<dim3(64, 32, 3), blk, 0, stream>>>(Wu, Wr, Wn, Wtur, Wtn);
  // 5. attnb = exp(prev @ tok^T / 32)   (mode 0; softmax denom dropped - LN
  //    is scale-invariant per row)
  k_gemm64<<<dim3(1, 32, 16), blk, 0, stream>>>(
      psb, 65536L, 0L, 1024, tok, 2097152L, 0L, 1024, 1024, 1,
      nullptr, nullptr, 0.03125f, 0,
      nullptr, 2048, 131072L, 0L, attnb, nullptr, nullptr, nullptr);
  // 6. routed partials (unnormalized)
  k_routed_mfma<<<dim3(2, 16, 16), blk, 0, stream>>>(attnb, tok, parts);
  // 7. both LayerNorms
  k_ln2<<<dim3(2048), blk, 0, stream>>>(prev, parts, g_st, be_st, g_in, be_in,
                                        conc, candA);
  // 8. merged u|r gates (mode 5)
  k_gemm64<<<dim3(16, 32, 1), blk, 0, stream>>>(
      conc, 0L, 0L, 2048, Wtur, 0L, 0L, 2048, 2048, 1,
      bu, br, 1.0f, 5,
      (void*)ubuf, 1024, 0L, 0L, candA, conc, nullptr, nullptr);
  // 9. new_state (mode 3)
  k_gemm64<<<dim3(16, 16, 1), blk, 0, stream>>>(
      candA, 0L, 0L, 2048, Wtn, 0L, 0L, 2048, 2048, 1,
      bn, nullptr, 1.0f, 3,
      (void*)ns, 1024, 0L, 0L, nullptr, nullptr, ubuf, prev);
  // 10. final LN -> output
  k_ln_out<<<dim3(1024), blk, 0, stream>>>(ns, g_o, be_o, out);
}